// Round 6
// baseline (117.080 us; speedup 1.0000x reference)
//
#include <hip/hip_runtime.h>
#include <hip/hip_bf16.h>

// CapsuleLayer on MI355X — R10: BARRIER-FREE main loop. R4-R9 (43-50us) all
// shared a per-kk 8/16-wave vmcnt+barrier rendezvous (m233 "2-phase stall");
// MfmaUtil*dur == theoretical MFMA min, so only overlap is missing. Changes:
// (1) B staged in REGISTERS (2-kk dbuf) via perfectly-coalesced 1KB fragment
//     loads from Wr2b, which k_reorder writes in exact MFMA-fragment order
//     [kk][cg][ks][ni][lane] (R5's direct-L2 failure was lane-strided
//     transactions, not volume) -> zero Bs LDS, ZERO mid-loop barriers.
// (2) As stride 68 ushorts: conflict-free banks (2p+4c+j) with NO XOR ->
//     every ds_read = one base VGPR + compile-time immediate; per-kk VALU ~0.
// Compiler emits counted per-wave vmcnt/lgkmcnt on the unrolled stream.
// b stays 0 (faithful torch bug) => one dense conv 64ci->128co, 5x5, pad 2;
// v = squash_z1(p/(8*cnt)); out [N, t1, z1, H, W].

#define CO 128

typedef __attribute__((ext_vector_type(8))) short bf16x8;
typedef __attribute__((ext_vector_type(4))) float f32x4;

// ---- W fp32 [t0][co][z0][5][5] -> Wr2b bf16 in MFMA-fragment order:
// idx = (((kk*2+cg)*2+ks)*4+ni)*512 + (q*16+m16)*8 + j
// where co = cg*64+ni*16+m16, ci = ks*32+q*8+j.
__global__ __launch_bounds__(256) void k_reorder(const float* __restrict__ Wsrc,
                                                 ushort* __restrict__ Wr2b) {
    int idx = blockIdx.x * 256 + threadIdx.x;   // 800 blocks = 25*128*64 exact
    int ci = idx & 63;
    int r  = idx >> 6;
    int co = r & 127;
    int kk = r >> 7;
    int t0 = ci >> 4, z0 = ci & 15;
    __hip_bfloat16 bb = __float2bfloat16(Wsrc[((t0 * CO + co) * 16 + z0) * 25 + kk]);
    int cg = co >> 6, ni = (co >> 4) & 3, m16 = co & 15;
    int ks = ci >> 5, q = (ci >> 3) & 3, j = ci & 7;
    int oi = ((((kk * 2 + cg) * 2 + ks) * 4 + ni) << 9) + ((q * 16 + m16) << 3) + j;
    Wr2b[oi] = *(ushort*)&bb;
}

// ---- main: grid 512 = 4(n) x 16(by: 8 rows) x 8(bx: 16 cols), 256 thr =
// 4 waves = rg2(4 h-rows) x cg2(64 co). As stride-68, read-only after one
// sync. B: per-wave register double-buffer, fragment loads 1KB coalesced.
__global__ __launch_bounds__(256) void k_caps(const float* __restrict__ u,
                                              const ushort* __restrict__ Wr2b,
                                              float* __restrict__ out) {
    __shared__ ushort As[240 * 68];      // 32640 B

    int tid = threadIdx.x;
    int bid = blockIdx.x;
    int bx = bid & 7, by = (bid >> 3) & 15, n = bid >> 7;
    int h0 = by * 8, w0 = bx * 16;

    int lane = tid & 63, wid = tid >> 6;
    int rg = wid >> 1;                   // h group (0..1)
    int cg = wid & 1;                    // co group
    int wm4  = rg * 4;
    int wn64 = cg * 64;
    int q = lane >> 4, m16 = lane & 15;

    // B fragment base for this wave: (kk,ks,ni) -> + kk*8192 + (ks*4+ni)*512
    const ushort* wp = Wr2b + ((size_t)cg * 4096) + lane * 8;

    bf16x8 bA[8], bB[8];                 // two kk-buffers, [ks*4+ni]
#define LOADB(dst, kk2)                                                  \
    {                                                                    \
        _Pragma("unroll") for (int ks_ = 0; ks_ < 2; ++ks_)              \
            _Pragma("unroll") for (int ni_ = 0; ni_ < 4; ++ni_)          \
                dst[ks_ * 4 + ni_] = *(const bf16x8*)(                   \
                    wp + (size_t)(kk2) * 8192 + (ks_ * 4 + ni_) * 512);  \
    }

    LOADB(bA, 0);                        // flies under the A staging

    // ---- A staging directly from u: 240 px x 8 octets, scalar ci-strided
    // loads (coalesced along w), cvt, ds_write_b128 at stride-68.
    for (int i = tid; i < 1920; i += 256) {
        int p = i >> 3, c = i & 7;
        int rr = p / 20, cc = p - rr * 20;
        int hh = h0 + rr - 2, ww = w0 + cc - 2;
        bf16x8 v = {};
        if (((unsigned)hh < 128u) & ((unsigned)ww < 128u)) {
            const float* up = u + (size_t)n * (64 * 128 * 128) + (size_t)hh * 128 + ww;
#pragma unroll
            for (int j = 0; j < 8; ++j) {
                __hip_bfloat16 bb = __float2bfloat16(up[(size_t)(c * 8 + j) * 16384]);
                v[j] = *(ushort*)&bb;
            }
        }
        *(bf16x8*)&As[p * 68 + c * 8] = v;
    }
    __syncthreads();                     // the ONLY barrier
    LOADB(bB, 1);

    // lane A base; all per-(kk,mi,ks) deltas are compile-time immediates:
    // offset = ((mi+kh)*20+kw)*68 + ks*32 ushorts, max 19712 B < 64K imm.
    const ushort* ap = As + (wm4 * 20 + m16) * 68 + q * 8;

    f32x4 acc[4][4] = {};

#pragma unroll
    for (int kk = 0; kk < 25; ++kk) {
        const int kh = kk / 5, kw = kk % 5;
#pragma unroll
        for (int ks = 0; ks < 2; ++ks) {
            bf16x8 a[4];
#pragma unroll
            for (int mi = 0; mi < 4; ++mi)
                a[mi] = *(const bf16x8*)(ap + ((mi + kh) * 20 + kw) * 68 + ks * 32);
#pragma unroll
            for (int mi = 0; mi < 4; ++mi)
#pragma unroll
                for (int ni = 0; ni < 4; ++ni)
                    acc[mi][ni] = __builtin_amdgcn_mfma_f32_16x16x32_bf16(
                        a[mi], (kk & 1) ? bB[ks * 4 + ni] : bA[ks * 4 + ni],
                        acc[mi][ni], 0, 0, 0);
        }
        if (kk < 23) {                   // refill the buffer just consumed
            if (kk & 1) { LOADB(bB, kk + 2); }
            else        { LOADB(bA, kk + 2); }
        }
    }
#undef LOADB

    // epilogue (R3-proven): scale 1/(8*cnt), squash over z1 (m16 lanes), store
    // D layout: row(m = image col) = q*4+reg, col(n = co) = m16
#pragma unroll
    for (int mi = 0; mi < 4; ++mi) {
        int h = h0 + wm4 + mi;
        int hlo = h - 2; if (hlo < 0) hlo = 0;
        int hhi = h + 2; if (hhi > 127) hhi = 127;
        float cnth = (float)(hhi - hlo + 1);
#pragma unroll
        for (int ni = 0; ni < 4; ++ni) {
            f32x4 cv = acc[mi][ni];
            float ov[4];
#pragma unroll
            for (int reg = 0; reg < 4; ++reg) {
                int w = w0 + q * 4 + reg;
                int wlo = w - 2; if (wlo < 0) wlo = 0;
                int whi = w + 2; if (whi > 127) whi = 127;
                float s = 1.f / (8.f * cnth * (float)(whi - wlo + 1));
                float pv = cv[reg] * s;
                float n2 = pv * pv;
                n2 += __shfl_xor(n2, 1);
                n2 += __shfl_xor(n2, 2);
                n2 += __shfl_xor(n2, 4);
                n2 += __shfl_xor(n2, 8);
                float fac = n2 / ((1.f + n2) * sqrtf(n2 + 1e-9f));
                ov[reg] = pv * fac;
            }
            int co = wn64 + ni * 16 + m16;
            *(float4*)(out + (((size_t)(n * CO + co)) << 14) + h * 128 + w0 + q * 4) =
                make_float4(ov[0], ov[1], ov[2], ov[3]);
        }
    }
}

extern "C" void kernel_launch(void* const* d_in, const int* in_sizes, int n_in,
                              void* d_out, int out_size, void* d_ws, size_t ws_size,
                              hipStream_t stream) {
    const float* u    = (const float*)d_in[0];
    const float* Wsrc = (const float*)d_in[1];
    float* out = (float*)d_out;
    ushort* Wr2b = (ushort*)d_ws;                      // 819200 B

    k_reorder<<<800, 256, 0, stream>>>(Wsrc, Wr2b);
    k_caps<<<512, 256, 0, stream>>>(u, Wr2b, out);
}

// Round 7
// 110.090 us; speedup vs baseline: 1.0635x; 1.0635x over previous
//
#include <hip/hip_runtime.h>
#include <hip/hip_bf16.h>

// CapsuleLayer on MI355X — R11: R6's fast A-path + R10's barrier-free loop.
// Post-mortem R10: MFMA-busy is pinned at ~10.2us in ALL variants; dur =
// floor/util. The variant-invariant cost was the in-kernel A-staging from
// fp32 u (8 lanes 512KB apart -> ~8 lines per load instr, ~2000 latency-bound
// txns per block, serialized before the loop). Fix: restore k_pre transpose
// (u -> ut bf16 [n][h][w][ci], vectorized), so caps staging = 1KB-contiguous
// wave reads. Keep reg-B barrier-free loop (R10) and ADD parity register
// double-buffering of A fragments (ds_reads for kk+1 issued before kk's
// MFMAs — MFMA blocks its wave, so this ILP must be explicit).
// b stays 0 (faithful torch bug) => one dense conv 64ci->128co, 5x5, pad 2;
// v = squash_z1(p/(8*cnt)); out [N, t1, z1, H, W].

#define CO 128

typedef __attribute__((ext_vector_type(8))) short bf16x8;
typedef __attribute__((ext_vector_type(4))) float f32x4;

// ---- fused prep:
//   blocks [0,800):    W fp32 [t0][co][z0][5][5] -> Wr2b bf16 fragment-order:
//                      oi = (((kk*2+cg)*2+ks)*4+ni)*512 + (q*16+m16)*8 + j
//                      (co = cg*64+ni*16+m16, ci = ks*32+q*8+j)
//   blocks [800,1824): u [n][ci][h][w] fp32 -> ut [n][h][w][ci] bf16
__global__ __launch_bounds__(256) void k_prep(const float* __restrict__ u,
                                              const float* __restrict__ Wsrc,
                                              ushort* __restrict__ ut,
                                              ushort* __restrict__ Wr2b) {
    __shared__ float lt[64][65];
    int b = blockIdx.x;
    int t = threadIdx.x;
    if (b < 800) {
        int idx = b * 256 + t;                  // 25*128*64 exact
        int ci = idx & 63;
        int r  = idx >> 6;
        int co = r & 127;
        int kk = r >> 7;
        int t0 = ci >> 4, z0 = ci & 15;
        __hip_bfloat16 bb = __float2bfloat16(Wsrc[((t0 * CO + co) * 16 + z0) * 25 + kk]);
        int cg = co >> 6, ni = (co >> 4) & 3, m16 = co & 15;
        int ks = ci >> 5, q = (ci >> 3) & 3, j = ci & 7;
        int oi = ((((kk * 2 + cg) * 2 + ks) * 4 + ni) << 9) + ((q * 16 + m16) << 3) + j;
        Wr2b[oi] = *(ushort*)&bb;
        return;
    }
    b -= 800;                                   // (n*128 + h)*2 + wchunk
    int wc = b & 1; int nh = b >> 1; int h = nh & 127; int n = nh >> 7;
    int w0 = wc * 64;
    // load: float4 per thread, 4 passes. lanes: ci = p*16 + (t>>4), w = (t&15)*4
    int ciL = t >> 4;
    int wl  = (t & 15) * 4;
    const float* up = u + (size_t)n * (64 * 128 * 128) + h * 128 + w0;
#pragma unroll
    for (int p = 0; p < 4; ++p) {
        int ci = p * 16 + ciL;
        float4 v = *(const float4*)(up + (size_t)ci * 16384 + wl);
        lt[wl + 0][ci] = v.x;
        lt[wl + 1][ci] = v.y;
        lt[wl + 2][ci] = v.z;
        lt[wl + 3][ci] = v.w;
    }
    __syncthreads();
    // store: bf16x8 (16B) per thread, 2 passes (1 KB contiguous per wave)
    ushort* op = ut + (((size_t)(n * 128 + h)) * 128 + w0) * 64;
#pragma unroll
    for (int p = 0; p < 2; ++p) {
        int item = p * 256 + t;
        int c8 = item & 7, w2 = item >> 3;
        bf16x8 vv;
#pragma unroll
        for (int j = 0; j < 8; ++j) {
            __hip_bfloat16 bb = __float2bfloat16(lt[w2][c8 * 8 + j]);
            vv[j] = *(ushort*)&bb;
        }
        *(bf16x8*)(op + (size_t)w2 * 64 + c8 * 8) = vv;
    }
}

// ---- main: grid 512 = 4(n) x 16(by: 8 rows) x 8(bx: 16 cols), 256 thr =
// 4 waves = rg2(4 h-rows) x cg2(64 co). As stride-68 (conflict-free, all
// ds_read offsets compile-time immediates). ZERO mid-loop barriers.
// A-frags: parity register dbuf (read kk+1 before kk's MFMAs).
// B-frags: parity register dbuf, 1KB-coalesced loads from fragment-ordered
// Wr2b (L2-resident), refilled 2 kk ahead.
__global__ __launch_bounds__(256) void k_caps(const ushort* __restrict__ ut,
                                              const ushort* __restrict__ Wr2b,
                                              float* __restrict__ out) {
    __shared__ ushort As[240 * 68];      // 32640 B

    int tid = threadIdx.x;
    int bid = blockIdx.x;
    int bx = bid & 7, by = (bid >> 3) & 15, n = bid >> 7;
    int h0 = by * 8, w0 = bx * 16;

    int lane = tid & 63, wid = tid >> 6;
    int rg = wid >> 1;                   // h group (0..1)
    int cg = wid & 1;                    // co group
    int wm4  = rg * 4;
    int wn64 = cg * 64;
    int q = lane >> 4, m16 = lane & 15;

    // B fragment base for this wave
    const ushort* wp = Wr2b + ((size_t)cg * 4096) + lane * 8;

    bf16x8 bA[8], bB[8];                 // kk-parity buffers, [ks*4+ni]
#define LOADB(dst, kk2)                                                  \
    {                                                                    \
        _Pragma("unroll") for (int ks_ = 0; ks_ < 2; ++ks_)              \
            _Pragma("unroll") for (int ni_ = 0; ni_ < 4; ++ni_)          \
                dst[ks_ * 4 + ni_] = *(const bf16x8*)(                   \
                    wp + (size_t)(kk2) * 8192 + (ks_ * 4 + ni_) * 512);  \
    }

    LOADB(bA, 0);                        // flies under the A staging

    // ---- A staging from ut: 1920 x 16B, 1KB-contiguous per wave pass.
    for (int i = tid; i < 1920; i += 256) {
        int p = i >> 3, c = i & 7;
        int rr = p / 20, cc = p - rr * 20;
        int hh = h0 + rr - 2, ww = w0 + cc - 2;
        bf16x8 v = {};
        if (((unsigned)hh < 128u) & ((unsigned)ww < 128u))
            v = *(const bf16x8*)(ut + (((size_t)(n * 128 + hh)) * 128 + ww) * 64 + c * 8);
        *(bf16x8*)&As[p * 68 + c * 8] = v;
    }
    __syncthreads();                     // the ONLY barrier
    LOADB(bB, 1);

    // lane A base; per-(kk,mi,ks) deltas are compile-time immediates.
    const ushort* ap = As + (wm4 * 20 + m16) * 68 + q * 8;

#define LOADA(dst, kk2)                                                     \
    {                                                                       \
        const int kh_ = (kk2) / 5, kw_ = (kk2) % 5;                         \
        _Pragma("unroll") for (int ks_ = 0; ks_ < 2; ++ks_)                 \
            _Pragma("unroll") for (int mi_ = 0; mi_ < 4; ++mi_)             \
                dst[ks_ * 4 + mi_] = *(const bf16x8*)(                      \
                    ap + ((mi_ + kh_) * 20 + kw_) * 68 + ks_ * 32);         \
    }

    bf16x8 aA[8], aB[8];                 // kk-parity A-frag buffers
    LOADA(aA, 0);

    f32x4 acc[4][4] = {};

#pragma unroll
    for (int kk = 0; kk < 25; ++kk) {
        // prefetch next kk's A frags BEFORE this kk's MFMAs
        if (kk < 24) {
            if (kk & 1) { LOADA(aA, kk + 1); }
            else        { LOADA(aB, kk + 1); }
        }
        const bf16x8* av = (kk & 1) ? aB : aA;
        const bf16x8* bv = (kk & 1) ? bB : bA;
#pragma unroll
        for (int ks = 0; ks < 2; ++ks)
#pragma unroll
            for (int mi = 0; mi < 4; ++mi)
#pragma unroll
                for (int ni = 0; ni < 4; ++ni)
                    acc[mi][ni] = __builtin_amdgcn_mfma_f32_16x16x32_bf16(
                        av[ks * 4 + mi], bv[ks * 4 + ni], acc[mi][ni], 0, 0, 0);
        // refill the B buffer just consumed (2 kk ahead)
        if (kk < 23) {
            if (kk & 1) { LOADB(bB, kk + 2); }
            else        { LOADB(bA, kk + 2); }
        }
    }
#undef LOADA
#undef LOADB

    // epilogue (R3-proven): scale 1/(8*cnt), squash over z1 (m16 lanes), store
    // D layout: row(m = image col) = q*4+reg, col(n = co) = m16
#pragma unroll
    for (int mi = 0; mi < 4; ++mi) {
        int h = h0 + wm4 + mi;
        int hlo = h - 2; if (hlo < 0) hlo = 0;
        int hhi = h + 2; if (hhi > 127) hhi = 127;
        float cnth = (float)(hhi - hlo + 1);
#pragma unroll
        for (int ni = 0; ni < 4; ++ni) {
            f32x4 cv = acc[mi][ni];
            float ov[4];
#pragma unroll
            for (int reg = 0; reg < 4; ++reg) {
                int w = w0 + q * 4 + reg;
                int wlo = w - 2; if (wlo < 0) wlo = 0;
                int whi = w + 2; if (whi > 127) whi = 127;
                float s = 1.f / (8.f * cnth * (float)(whi - wlo + 1));
                float pv = cv[reg] * s;
                float n2 = pv * pv;
                n2 += __shfl_xor(n2, 1);
                n2 += __shfl_xor(n2, 2);
                n2 += __shfl_xor(n2, 4);
                n2 += __shfl_xor(n2, 8);
                float fac = n2 / ((1.f + n2) * sqrtf(n2 + 1e-9f));
                ov[reg] = pv * fac;
            }
            int co = wn64 + ni * 16 + m16;
            *(float4*)(out + (((size_t)(n * CO + co)) << 14) + h * 128 + w0 + q * 4) =
                make_float4(ov[0], ov[1], ov[2], ov[3]);
        }
    }
}

extern "C" void kernel_launch(void* const* d_in, const int* in_sizes, int n_in,
                              void* d_out, int out_size, void* d_ws, size_t ws_size,
                              hipStream_t stream) {
    const float* u    = (const float*)d_in[0];
    const float* Wsrc = (const float*)d_in[1];
    float* out = (float*)d_out;
    ushort* Wr2b = (ushort*)d_ws;                      // 409600 B
    ushort* ut   = (ushort*)((char*)d_ws + 409600);    // 8388608 B

    k_prep<<<1824, 256, 0, stream>>>(u, Wsrc, ut, Wr2b);
    k_caps<<<512, 256, 0, stream>>>(ut, Wr2b, out);
}